// Round 2
// baseline (755.006 us; speedup 1.0000x reference)
//
#include <hip/hip_runtime.h>
#include <math.h>

#define UNITS 64
#define TT 100
#define NB 16          // batch rows per tile = one MFMA M-tile
#define NTH 512        // 8 waves: wave w = (cg = w>>1 colgroup, hf = w&1 row-half)
#define HSTR 72        // hbuf row stride in halves (identity rows: b128 reads conflict-free)
#define XQSTR 18       // xt quad stride per timestep (16 rows + 2 pad -> conflict-free)

typedef _Float16 half8 __attribute__((ext_vector_type(8)));
typedef _Float16 half4 __attribute__((ext_vector_type(4)));
typedef float floatx4 __attribute__((ext_vector_type(4)));

#define LOG2E 1.44269504088896f

__device__ __forceinline__ float rcp_fast(float x) { return __builtin_amdgcn_rcpf(x); }
__device__ __forceinline__ float exp2_fast(float x) { return __builtin_amdgcn_exp2f(x); }

// Single-dispatch design note (rounds 5..14 ledger):
//  - every extra graph node costs ~30-75 us on this harness -> ONE node total.
//  - cross-block sync at 1024-block scale costs 300-1300 us -> NONE here.
//  - length-sorting never reduced LSTM wall-clock -> compute lengths per-block.
// Round 15: prescaled weights (-LOG2E / -2LOG2E), scaled cell domain d=-2LOG2E*c,
//  AX q-select removed (zero B-rows make garbage*0 safe). dur 165->150.
// Round 16 (this round):
//  - hslot row permutation REVERTED: it moved bank conflicts from writes to reads
//    (counter 3.78M->3.59M, net zero). Identity rows keep b128 reads conflict-free;
//    write conflicts are a ~4%/CU tax we accept for now.
//  - occupancy was the real limiter: 16-row tile @ 4 waves pins the chip at
//    16 waves/CU (4/SIMD) -> 35% VALU-port idle from trans-latency + barrier convoy.
//    Now 8 waves/tile: wave (cg,hf) duplicates the 12 MFMAs of colgroup cg
//    (MFMA pipe only 21% busy - duplication is free) and activates only rows
//    4q+2hf+{0,1} (compile-time acc indices via wave-uniform hf branch; trans work
//    still done exactly once chip-wide). 8192 waves = 32/CU = 100% static occupancy.
__global__ __launch_bounds__(NTH, 8) void lstm_kernel(
    const float* __restrict__ x,    // (B,100,3)
    const float* __restrict__ W,    // (3,256)
    const float* __restrict__ U,    // (64,256)
    const float* __restrict__ bias, // (256,)
    const float* __restrict__ W1,   // (64,64)
    const float* __restrict__ b1,   // (64,)
    const float* __restrict__ W2,   // (64,5)
    const float* __restrict__ b2,   // (5,)
    float* __restrict__ out, int B)
{
    __shared__ __align__(16) _Float16 hb[2][NB * HSTR];   // double-buffered h (f16)
    __shared__ __align__(16) _Float16 xt[TT * XQSTR * 4]; // staged x tile: quads {x0,x1,x2,1}
    __shared__ int llen_s[NB];                            // per-row lengths (this tile)
    __shared__ float h1buf[NB * 64];
    __shared__ float logitbuf[NB * 5];

    const int tid = threadIdx.x;
    const int w   = tid >> 6;
    const int cg  = w >> 1;     // colgroup: units [16cg, 16cg+16)
    const int hf  = w & 1;      // row-half: this wave activates rows 4q + 2hf + {0,1}
    const int l   = tid & 63;
    const int q   = l >> 4;
    const int cnl = l & 15;
    const int b0  = blockIdx.x * NB;
    const int grp = tid >> 5;   // row within tile (32 lanes/row now)
    const int sub = tid & 31;   // lane within row

    // ---- in-block per-row lengths: 32 lanes/row, strided, coalesced ----
    {
        const float* xp = x + (size_t)(b0 + grp) * (TT * 3);
        int m = 0;
        for (int t = sub; t < TT; t += 32) {   // 12B/lane contiguous
            const float a = xp[3*t], b = xp[3*t+1], c = xp[3*t+2];
            if (a != 0.0f || b != 0.0f || c != 0.0f) m = t + 1;
        }
        #pragma unroll
        for (int off = 16; off; off >>= 1) m = max(m, __shfl_down(m, off, 32));
        if (sub == 0) llen_s[grp] = m;
    }
    for (int i = tid; i < NB * HSTR; i += NTH) hb[0][i] = (_Float16)0.0f;
    __syncthreads();   // llen_s visible before ANY reader

    int maxlen = 0, minlen = TT;
    #pragma unroll
    for (int i = 0; i < NB; ++i) {             // LDS broadcast reads, cheap
        const int v = llen_s[i];
        maxlen = max(maxlen, v);
        minlen = min(minlen, v);
    }
    maxlen = (maxlen < 0) ? 0 : ((maxlen > TT) ? TT : maxlen);
    minlen = (minlen < 0) ? 0 : ((minlen > maxlen) ? maxlen : minlen);
    int rl[2];
    #pragma unroll
    for (int r2 = 0; r2 < 2; ++r2) rl[r2] = llen_s[4*q + 2*hf + r2];

    // ---- stage x tile as f16 quads {x0,x1,x2,1} ----
    {
        const float* xp = x + (size_t)(b0 + grp) * (TT * 3);
        for (int t = sub; t < maxlen; t += 32) {
            const float a = xp[3*t], b = xp[3*t+1], c = xp[3*t+2];
            half4 v = { (_Float16)a, (_Float16)b, (_Float16)c, (_Float16)1.0f };
            *(half4*)&xt[(t * XQSTR + grp) * 4] = v;
        }
    }

    // ---- extended-K B fragments: rows 0..63=U, 64..66=W, 67=bias, 68..95=0.
    // B-frag (16x16x32): lane holds B[k=32kb+8q+j][zc].
    // PRESCALED: i,f,o columns by -LOG2E, g columns by -2*LOG2E:
    //   sigmoid: rcp(1 + exp2(acc));  tanh(g): 2*rcp(1+exp2(acc)) - 1.
    half8 Bf[4][3];
    {
        const float gscale[4] = { -LOG2E, -LOG2E, -2.0f * LOG2E, -LOG2E };
        #pragma unroll
        for (int g = 0; g < 4; ++g) {
            const int zc = 64 * g + 16 * cg + cnl;
            #pragma unroll
            for (int kb = 0; kb < 3; ++kb)
                #pragma unroll
                for (int j = 0; j < 8; ++j) {
                    const int k = 32 * kb + 8 * q + j;
                    float v = 0.0f;
                    if (k < 64)       v = U[k * 256 + zc];
                    else if (k < 67)  v = W[(k - 64) * 256 + zc];
                    else if (k == 67) v = bias[zc];
                    Bf[g][kb][j] = (_Float16)(v * gscale[g]);
                }
        }
    }

    // cell state in scaled domain: d = -2*LOG2E * c  (d(0) = 0); 2 rows per wave
    float d4[2] = {0.0f, 0.0f};
    _Float16 hcur[2] = {(_Float16)0.0f, (_Float16)0.0f};
    const floatx4 zero4 = {0.0f, 0.0f, 0.0f, 0.0f};

    const int rsl = cnl * HSTR;             // identity rows: A-reads conflict-free
    int wr[2];
    #pragma unroll
    for (int r2 = 0; r2 < 2; ++r2)
        wr[r2] = (4*q + 2*hf + r2) * HSTR + 16*cg + cnl;

    __syncthreads();   // staging + hb[0] zero visible

// one cell update; RR = compile-time acc row index, RIX = per-wave state slot (0/1)
#define CELL_LIVE(RR, RIX)                                                    \
    {                                                                         \
        const float iv = rcp_fast(1.0f + exp2_fast(acc[0][RR]));              \
        const float fv = rcp_fast(1.0f + exp2_fast(acc[1][RR]));              \
        const float gq = rcp_fast(1.0f + exp2_fast(acc[2][RR]));              \
        const float ov = rcp_fast(1.0f + exp2_fast(acc[3][RR]));              \
        const float gs = __builtin_fmaf(-4.0f * LOG2E, gq, 2.0f * LOG2E);     \
        const float dn = __builtin_fmaf(fv, d4[RIX], iv * gs);                \
        d4[RIX] = dn;                                                         \
        const float th = __builtin_fmaf(2.0f, rcp_fast(1.0f + exp2_fast(dn)), -1.0f); \
        hcur[RIX] = (_Float16)(ov * th);                                      \
        hbn[wr[RIX]] = hcur[RIX];                                             \
    }

#define CELL_MASK(RR, RIX)                                                    \
    {                                                                         \
        const bool live = (t < rl[RIX]);                                      \
        const float iv = rcp_fast(1.0f + exp2_fast(acc[0][RR]));              \
        const float fv = rcp_fast(1.0f + exp2_fast(acc[1][RR]));              \
        const float gq = rcp_fast(1.0f + exp2_fast(acc[2][RR]));              \
        const float ov = rcp_fast(1.0f + exp2_fast(acc[3][RR]));              \
        const float gs = __builtin_fmaf(-4.0f * LOG2E, gq, 2.0f * LOG2E);     \
        const float dn = __builtin_fmaf(fv, d4[RIX], iv * gs);                \
        d4[RIX] = live ? dn : d4[RIX];                                        \
        const float th = __builtin_fmaf(2.0f, rcp_fast(1.0f + exp2_fast(dn)), -1.0f); \
        const _Float16 hn = (_Float16)(ov * th);                              \
        hcur[RIX] = live ? hn : hcur[RIX];                                    \
        hbn[wr[RIX]] = hcur[RIX];                                             \
    }

    int t = 0;

    // ---- unmasked main loop: all 16 rows live for t < minlen ----
    #pragma unroll 1
    for (; t < minlen; ++t) {
        const _Float16* hbc = hb[t & 1];
        _Float16*       hbn = hb[(t + 1) & 1];

        const half8 A0 = *(const half8*)&hbc[rsl + 8 * q];
        const half8 A1 = *(const half8*)&hbc[rsl + 32 + 8 * q];
        const half4 x4 = *(const half4*)&xt[(t * XQSTR + cnl) * 4];
        const half8 AX = { x4[0], x4[1], x4[2], x4[3],
                           (_Float16)0.0f, (_Float16)0.0f, (_Float16)0.0f, (_Float16)0.0f };

        floatx4 acc[4];
        #pragma unroll
        for (int g = 0; g < 4; ++g) {
            acc[g] = __builtin_amdgcn_mfma_f32_16x16x32_f16(AX, Bf[g][2], zero4, 0, 0, 0);
            acc[g] = __builtin_amdgcn_mfma_f32_16x16x32_f16(A0, Bf[g][0], acc[g], 0, 0, 0);
            acc[g] = __builtin_amdgcn_mfma_f32_16x16x32_f16(A1, Bf[g][1], acc[g], 0, 0, 0);
        }

        if (hf == 0) { CELL_LIVE(0, 0) CELL_LIVE(1, 1) }   // wave-uniform branch
        else         { CELL_LIVE(2, 0) CELL_LIVE(3, 1) }
        __syncthreads();
    }

    // ---- masked tail: rows die as t reaches their length ----
    #pragma unroll 1
    for (; t < maxlen; ++t) {
        const _Float16* hbc = hb[t & 1];
        _Float16*       hbn = hb[(t + 1) & 1];

        const half8 A0 = *(const half8*)&hbc[rsl + 8 * q];
        const half8 A1 = *(const half8*)&hbc[rsl + 32 + 8 * q];
        const half4 x4 = *(const half4*)&xt[(t * XQSTR + cnl) * 4];
        const half8 AX = { x4[0], x4[1], x4[2], x4[3],
                           (_Float16)0.0f, (_Float16)0.0f, (_Float16)0.0f, (_Float16)0.0f };

        floatx4 acc[4];
        #pragma unroll
        for (int g = 0; g < 4; ++g) {
            acc[g] = __builtin_amdgcn_mfma_f32_16x16x32_f16(AX, Bf[g][2], zero4, 0, 0, 0);
            acc[g] = __builtin_amdgcn_mfma_f32_16x16x32_f16(A0, Bf[g][0], acc[g], 0, 0, 0);
            acc[g] = __builtin_amdgcn_mfma_f32_16x16x32_f16(A1, Bf[g][1], acc[g], 0, 0, 0);
        }

        if (hf == 0) { CELL_MASK(0, 0) CELL_MASK(1, 1) }
        else         { CELL_MASK(2, 0) CELL_MASK(3, 1) }
        __syncthreads();
    }

    const _Float16* hbL = hb[maxlen & 1];

    // ---- epilogue: h1 = relu(h @ W1 + b1) ----
    {
        const int j  = tid & 63;
        const int bb = tid >> 6;           // 0..7
        const float bj = b1[j];
        #pragma unroll
        for (int p = 0; p < NB / 8; ++p) {
            const int b = p * 8 + bb;
            float acc = bj;
            #pragma unroll 8
            for (int k = 0; k < UNITS; ++k)
                acc += (float)hbL[b * HSTR + k] * W1[k * 64 + j];
            h1buf[b * 64 + j] = fmaxf(acc, 0.0f);
        }
    }
    __syncthreads();

    if (tid < NB * 5) {
        const int b = tid / 5, s = tid % 5;
        float acc = b2[s];
        for (int j = 0; j < 64; ++j)
            acc += h1buf[b * 64 + j] * W2[j * 5 + s];
        logitbuf[b * 5 + s] = acc;
    }
    __syncthreads();

    if (tid < NB) {
        const int gb = b0 + tid;   // identity mapping — no permutation
        const float l0 = logitbuf[tid * 5 + 0];
        const float l1 = logitbuf[tid * 5 + 1];
        const float l2 = logitbuf[tid * 5 + 2];
        const float l3 = logitbuf[tid * 5 + 3];
        const float l4 = logitbuf[tid * 5 + 4];
        const float m  = fmaxf(fmaxf(fmaxf(l0, l1), fmaxf(l2, l3)), l4);
        const float e0 = __expf(l0 - m), e1 = __expf(l1 - m), e2 = __expf(l2 - m);
        const float e3 = __expf(l3 - m), e4 = __expf(l4 - m);
        const float rs = 1.0f / (e0 + e1 + e2 + e3 + e4);
        out[(size_t)gb * 5 + 0] = e0 * rs;
        out[(size_t)gb * 5 + 1] = e1 * rs;
        out[(size_t)gb * 5 + 2] = e2 * rs;
        out[(size_t)gb * 5 + 3] = e3 * rs;
        out[(size_t)gb * 5 + 4] = e4 * rs;
    }
#undef CELL_LIVE
#undef CELL_MASK
}

extern "C" void kernel_launch(void* const* d_in, const int* in_sizes, int n_in,
                              void* d_out, int out_size, void* d_ws, size_t ws_size,
                              hipStream_t stream) {
    const float* x  = (const float*)d_in[0];
    const float* W  = (const float*)d_in[1];
    const float* U  = (const float*)d_in[2];
    const float* b  = (const float*)d_in[3];
    const float* W1 = (const float*)d_in[4];
    const float* b1 = (const float*)d_in[5];
    const float* W2 = (const float*)d_in[6];
    const float* b2 = (const float*)d_in[7];
    float* out = (float*)d_out;

    const int B = in_sizes[0] / (TT * 3);   // 16384

    lstm_kernel<<<dim3(B / NB), dim3(NTH), 0, stream>>>(
        x, W, U, b, W1, b1, W2, b2, out, B);
}

// Round 3
// 198.180 us; speedup vs baseline: 3.8097x; 3.8097x over previous
//
#include <hip/hip_runtime.h>
#include <math.h>

#define UNITS 64
#define TT 100
#define NB 16          // batch rows per tile = one MFMA M-tile
#define NTH 256        // 4 waves; wave w owns unit-columns [16w,16w+16) for all 4 gates
#define HSTR 72        // hbuf row stride in halves (identity rows: b128 reads 2-way = free)
#define XQSTR 18       // xt quad stride per timestep (16 rows + 2 pad -> conflict-free)

typedef _Float16 half8 __attribute__((ext_vector_type(8)));
typedef _Float16 half4 __attribute__((ext_vector_type(4)));
typedef float floatx4 __attribute__((ext_vector_type(4)));

#define LOG2E 1.44269504088896f

__device__ __forceinline__ float rcp_fast(float x) { return __builtin_amdgcn_rcpf(x); }
__device__ __forceinline__ float exp2_fast(float x) { return __builtin_amdgcn_exp2f(x); }

// Session ledger (key structural facts, do not re-derive):
//  - ONE dispatch total: extra graph nodes cost 30-75 us; cross-block sync 300-1300 us.
//  - length-sorting / load-balancing is structurally dead: M=16 MFMA tile forces
//    16-row blocks, 4-gate-complete columns force 4 waves, grid is exactly-resident
//    (1024 blocks = 4/CU) -> no backfill pool, CU wall-clock = max-tile ~97 steps.
//  - r16 (8 waves via launch_bounds(512,8)) FAILED: VGPR cap 64 < ~91 needed ->
//    Bf spilled to scratch -> 1.5 GB HBM/dispatch, 731 us. This layout's floor is
//    ~91 VGPR -> 4 waves/SIMD ceiling. Do NOT retry 8-wave without shrinking Bf.
//  - hslot write-permutation (r15) moved conflicts from writes to reads, net zero.
//    Write conflicts (~3.6M cyc, ~4%) are an accepted tax; reads must stay clean.
//  - trans ops issue at ~8 cyc/wave (quarter rate): 5 exp2 + 5 rcp = 80 of ~100
//    issue-cyc per cell -> trans count is THE lever while VALU-issue-bound.
// Round 17 (this round): pair-shared reciprocals, 10 -> 8 trans/cell:
//    sigma(i)*tanh(g) = (1-eg)/((1+ei)(1+eg))   [one rcp for i,g]
//    sigma(o)*tanh(c') = (1-ed)/((1+eo)(1+ed))  [one rcp for o,c]
//    f-gate keeps its own rcp. Bounded: |z|<=~12 -> e<=2^18, pair products <=2^37.
//    fminf(dn,126) guards the only unbounded path (cell recurrence); exact at
//    saturation since ed cancels in the ratio.
__global__ __launch_bounds__(NTH, 4) void lstm_kernel(
    const float* __restrict__ x,    // (B,100,3)
    const float* __restrict__ W,    // (3,256)
    const float* __restrict__ U,    // (64,256)
    const float* __restrict__ bias, // (256,)
    const float* __restrict__ W1,   // (64,64)
    const float* __restrict__ b1,   // (64,)
    const float* __restrict__ W2,   // (64,5)
    const float* __restrict__ b2,   // (5,)
    float* __restrict__ out, int B)
{
    __shared__ __align__(16) _Float16 hb[2][NB * HSTR];   // double-buffered h (f16)
    __shared__ __align__(16) _Float16 xt[TT * XQSTR * 4]; // staged x tile: quads {x0,x1,x2,1}
    __shared__ int llen_s[NB];                            // per-row lengths (this tile)
    __shared__ float h1buf[NB * 64];
    __shared__ float logitbuf[NB * 5];

    const int tid = threadIdx.x;
    const int w   = tid >> 6;
    const int l   = tid & 63;
    const int q   = l >> 4;
    const int cnl = l & 15;
    const int b0  = blockIdx.x * NB;
    const int grp = tid >> 4;   // row within tile
    const int sub = tid & 15;   // lane within row

    // ---- in-block per-row lengths: 16 lanes/row, strided, coalesced ----
    {
        const float* xp = x + (size_t)(b0 + grp) * (TT * 3);
        int m = 0;
        for (int t = sub; t < TT; t += 16) {   // 12B/lane contiguous
            const float a = xp[3*t], b = xp[3*t+1], c = xp[3*t+2];
            if (a != 0.0f || b != 0.0f || c != 0.0f) m = t + 1;
        }
        #pragma unroll
        for (int off = 8; off; off >>= 1) m = max(m, __shfl_down(m, off, 16));
        if (sub == 0) llen_s[grp] = m;
    }
    for (int i = tid; i < NB * HSTR; i += NTH) hb[0][i] = (_Float16)0.0f;
    __syncthreads();   // llen_s visible before ANY reader

    int maxlen = 0, minlen = TT;
    #pragma unroll
    for (int i = 0; i < NB; ++i) {             // LDS broadcast reads, cheap
        const int v = llen_s[i];
        maxlen = max(maxlen, v);
        minlen = min(minlen, v);
    }
    maxlen = (maxlen < 0) ? 0 : ((maxlen > TT) ? TT : maxlen);
    minlen = (minlen < 0) ? 0 : ((minlen > maxlen) ? maxlen : minlen);
    int rl[4];
    #pragma unroll
    for (int r = 0; r < 4; ++r) rl[r] = llen_s[4*q + r];

    // ---- stage x tile as f16 quads {x0,x1,x2,1} ----
    {
        const float* xp = x + (size_t)(b0 + grp) * (TT * 3);
        for (int t = sub; t < maxlen; t += 16) {
            const float a = xp[3*t], b = xp[3*t+1], c = xp[3*t+2];
            half4 v = { (_Float16)a, (_Float16)b, (_Float16)c, (_Float16)1.0f };
            *(half4*)&xt[(t * XQSTR + grp) * 4] = v;
        }
    }

    // ---- extended-K B fragments: rows 0..63=U, 64..66=W, 67=bias, 68..95=0.
    // B-frag (16x16x32): lane holds B[k=32kb+8q+j][zc].
    // PRESCALED: i,f,o columns by -LOG2E, g columns by -2*LOG2E:
    //   ei = exp2(acc_i) = exp(-z_i), eg = exp2(acc_g) = exp(-2 z_g), etc.
    half8 Bf[4][3];
    {
        const float gscale[4] = { -LOG2E, -LOG2E, -2.0f * LOG2E, -LOG2E };
        #pragma unroll
        for (int g = 0; g < 4; ++g) {
            const int zc = 64 * g + 16 * w + cnl;
            #pragma unroll
            for (int kb = 0; kb < 3; ++kb)
                #pragma unroll
                for (int j = 0; j < 8; ++j) {
                    const int k = 32 * kb + 8 * q + j;
                    float v = 0.0f;
                    if (k < 64)       v = U[k * 256 + zc];
                    else if (k < 67)  v = W[(k - 64) * 256 + zc];
                    else if (k == 67) v = bias[zc];
                    Bf[g][kb][j] = (_Float16)(v * gscale[g]);
                }
        }
    }

    // cell state in scaled domain: d = -2*LOG2E * c  (d(0) = 0)
    float d4[4] = {0.0f, 0.0f, 0.0f, 0.0f};
    _Float16 hcur[4] = {(_Float16)0.0f, (_Float16)0.0f, (_Float16)0.0f, (_Float16)0.0f};
    const floatx4 zero4 = {0.0f, 0.0f, 0.0f, 0.0f};

    const int rsl = cnl * HSTR;             // identity rows: A-reads 2-way = free
    int wr[4];
    #pragma unroll
    for (int r = 0; r < 4; ++r) wr[r] = (4*q + r) * HSTR + 16*w + cnl;

    __syncthreads();   // staging + hb[0] zero visible

    int t = 0;

    // ---- unmasked main loop: all 16 rows live for t < minlen ----
    #pragma unroll 1
    for (; t < minlen; ++t) {
        const _Float16* hbc = hb[t & 1];
        _Float16*       hbn = hb[(t + 1) & 1];

        const half8 A0 = *(const half8*)&hbc[rsl + 8 * q];
        const half8 A1 = *(const half8*)&hbc[rsl + 32 + 8 * q];
        // all lanes read the q=0 quad (same-addr broadcast); q>=1 B-rows are zero
        const half4 x4 = *(const half4*)&xt[(t * XQSTR + cnl) * 4];
        const half8 AX = { x4[0], x4[1], x4[2], x4[3],
                           (_Float16)0.0f, (_Float16)0.0f, (_Float16)0.0f, (_Float16)0.0f };

        floatx4 acc[4];
        #pragma unroll
        for (int g = 0; g < 4; ++g) {
            acc[g] = __builtin_amdgcn_mfma_f32_16x16x32_f16(AX, Bf[g][2], zero4, 0, 0, 0);
            acc[g] = __builtin_amdgcn_mfma_f32_16x16x32_f16(A0, Bf[g][0], acc[g], 0, 0, 0);
            acc[g] = __builtin_amdgcn_mfma_f32_16x16x32_f16(A1, Bf[g][1], acc[g], 0, 0, 0);
        }

        #pragma unroll
        for (int r = 0; r < 4; ++r) {
            const float ei = exp2_fast(acc[0][r]);
            const float ef = exp2_fast(acc[1][r]);
            const float eg = exp2_fast(acc[2][r]);
            const float eo = exp2_fast(acc[3][r]);
            const float Ag = 1.0f + eg;
            const float P  = __builtin_fmaf(ei, Ag, Ag);            // (1+ei)(1+eg)
            const float tg = __builtin_fmaf(2.0f*LOG2E, eg, -2.0f*LOG2E); // -2L(1-eg)
            const float ig = tg * rcp_fast(P);                      // sig(i)*(-2L*tanh(g))
            const float fv = rcp_fast(1.0f + ef);                   // sig(f)
            const float dn = __builtin_fmaf(fv, d4[r], ig);
            d4[r] = dn;
            const float ed = exp2_fast(fminf(dn, 126.0f));          // overflow guard (exact)
            const float D2 = 1.0f + ed;
            const float Q  = __builtin_fmaf(eo, D2, D2);            // (1+eo)(1+ed)
            const float hv = (1.0f - ed) * rcp_fast(Q);             // sig(o)*tanh(c')
            hcur[r] = (_Float16)hv;
            hbn[wr[r]] = hcur[r];
        }
        __syncthreads();
    }

    // ---- masked tail: rows die as t reaches their length ----
    #pragma unroll 1
    for (; t < maxlen; ++t) {
        const _Float16* hbc = hb[t & 1];
        _Float16*       hbn = hb[(t + 1) & 1];

        const half8 A0 = *(const half8*)&hbc[rsl + 8 * q];
        const half8 A1 = *(const half8*)&hbc[rsl + 32 + 8 * q];
        const half4 x4 = *(const half4*)&xt[(t * XQSTR + cnl) * 4];
        const half8 AX = { x4[0], x4[1], x4[2], x4[3],
                           (_Float16)0.0f, (_Float16)0.0f, (_Float16)0.0f, (_Float16)0.0f };

        floatx4 acc[4];
        #pragma unroll
        for (int g = 0; g < 4; ++g) {
            acc[g] = __builtin_amdgcn_mfma_f32_16x16x32_f16(AX, Bf[g][2], zero4, 0, 0, 0);
            acc[g] = __builtin_amdgcn_mfma_f32_16x16x32_f16(A0, Bf[g][0], acc[g], 0, 0, 0);
            acc[g] = __builtin_amdgcn_mfma_f32_16x16x32_f16(A1, Bf[g][1], acc[g], 0, 0, 0);
        }

        #pragma unroll
        for (int r = 0; r < 4; ++r) {
            const bool live = (t < rl[r]);   // mask == (t < len): interior all-zero x measure 0
            const float ei = exp2_fast(acc[0][r]);
            const float ef = exp2_fast(acc[1][r]);
            const float eg = exp2_fast(acc[2][r]);
            const float eo = exp2_fast(acc[3][r]);
            const float Ag = 1.0f + eg;
            const float P  = __builtin_fmaf(ei, Ag, Ag);
            const float tg = __builtin_fmaf(2.0f*LOG2E, eg, -2.0f*LOG2E);
            const float ig = tg * rcp_fast(P);
            const float fv = rcp_fast(1.0f + ef);
            const float dn = __builtin_fmaf(fv, d4[r], ig);
            d4[r] = live ? dn : d4[r];
            const float ed = exp2_fast(fminf(dn, 126.0f));
            const float D2 = 1.0f + ed;
            const float Q  = __builtin_fmaf(eo, D2, D2);
            const float hv = (1.0f - ed) * rcp_fast(Q);
            const _Float16 hn = (_Float16)hv;
            hcur[r] = live ? hn : hcur[r];
            hbn[wr[r]] = hcur[r];
        }
        __syncthreads();
    }

    const _Float16* hbL = hb[maxlen & 1];

    // ---- epilogue: h1 = relu(h @ W1 + b1) ----
    {
        const int j  = tid & 63;
        const int bb = tid >> 6;
        const float bj = b1[j];
        #pragma unroll
        for (int p = 0; p < NB / 4; ++p) {
            const int b = p * 4 + bb;
            float acc = bj;
            #pragma unroll 8
            for (int k = 0; k < UNITS; ++k)
                acc += (float)hbL[b * HSTR + k] * W1[k * 64 + j];
            h1buf[b * 64 + j] = fmaxf(acc, 0.0f);
        }
    }
    __syncthreads();

    if (tid < NB * 5) {
        const int b = tid / 5, s = tid % 5;
        float acc = b2[s];
        for (int j = 0; j < 64; ++j)
            acc += h1buf[b * 64 + j] * W2[j * 5 + s];
        logitbuf[b * 5 + s] = acc;
    }
    __syncthreads();

    if (tid < NB) {
        const int gb = b0 + tid;   // identity mapping — no permutation
        const float l0 = logitbuf[tid * 5 + 0];
        const float l1 = logitbuf[tid * 5 + 1];
        const float l2 = logitbuf[tid * 5 + 2];
        const float l3 = logitbuf[tid * 5 + 3];
        const float l4 = logitbuf[tid * 5 + 4];
        const float m  = fmaxf(fmaxf(fmaxf(l0, l1), fmaxf(l2, l3)), l4);
        const float e0 = __expf(l0 - m), e1 = __expf(l1 - m), e2 = __expf(l2 - m);
        const float e3 = __expf(l3 - m), e4 = __expf(l4 - m);
        const float rs = 1.0f / (e0 + e1 + e2 + e3 + e4);
        out[(size_t)gb * 5 + 0] = e0 * rs;
        out[(size_t)gb * 5 + 1] = e1 * rs;
        out[(size_t)gb * 5 + 2] = e2 * rs;
        out[(size_t)gb * 5 + 3] = e3 * rs;
        out[(size_t)gb * 5 + 4] = e4 * rs;
    }
}

extern "C" void kernel_launch(void* const* d_in, const int* in_sizes, int n_in,
                              void* d_out, int out_size, void* d_ws, size_t ws_size,
                              hipStream_t stream) {
    const float* x  = (const float*)d_in[0];
    const float* W  = (const float*)d_in[1];
    const float* U  = (const float*)d_in[2];
    const float* b  = (const float*)d_in[3];
    const float* W1 = (const float*)d_in[4];
    const float* b1 = (const float*)d_in[5];
    const float* W2 = (const float*)d_in[6];
    const float* b2 = (const float*)d_in[7];
    float* out = (float*)d_out;

    const int B = in_sizes[0] / (TT * 3);   // 16384

    lstm_kernel<<<dim3(B / NB), dim3(NTH), 0, stream>>>(
        x, W, U, b, W1, b1, W2, b2, out, B);
}